// Round 9
// baseline (260.349 us; speedup 1.0000x reference)
//
#include <hip/hip_runtime.h>
#include <hip/hip_bf16.h>

// Problem constants
#define BB 2
#define TT 2048
#define CC 768
#define HH 8
#define DD 96
#define N3 2304   // 3*C
#define BH (BB*HH)
#define PANEL 4096   // ushorts per 128x32 LDS panel

typedef __bf16 bf16x8 __attribute__((ext_vector_type(8)));
typedef float f32x4 __attribute__((ext_vector_type(4)));

__device__ __forceinline__ ushort f2bf(float f) {
    unsigned u = __builtin_bit_cast(unsigned, f);
    u += 0x7fffu + ((u >> 16) & 1u);   // round-to-nearest-even
    return (ushort)(u >> 16);
}
// pack two floats to bf16x2 (truncating — bias cancels in P/l ratio)
__device__ __forceinline__ unsigned pk2(float a, float b) {
    return (__builtin_bit_cast(unsigned, a) >> 16) |
           (__builtin_bit_cast(unsigned, b) & 0xFFFF0000u);
}

// ---------------------------------------------------------------------------
// Kernel: fused prepass. Block-uniform branch on blockIdx.x ranges:
//  [0,1536)        : x fp32 -> xb bf16 (flat, 8/thread)
//  [1536,1968)     : W_attn [768][2304] -> Wat bf16 [2304][768] (transpose)
//  [1968,2112)     : W_proj [768][768]  -> Wpt bf16 [768][768]  (transpose)
//  [2112,5184)     : zero Yacc (4096*768 fp32)
//  [5184,5216)     : zero Lsum (16*2048 fp32)
// ---------------------------------------------------------------------------
#define PREP_BLOCKS 5216
__global__ __launch_bounds__(256) void prep_kernel(
    const float* __restrict__ x, const float* __restrict__ W_attn,
    const float* __restrict__ W_proj,
    ushort* __restrict__ xb, ushort* __restrict__ Wat, ushort* __restrict__ Wpt,
    float* __restrict__ Yacc, float* __restrict__ Lsum)
{
    __shared__ ushort t[64][66];
    const int bid = blockIdx.x;
    const int tid = threadIdx.x;

    if (bid < 1536) {
        const size_t i = ((size_t)bid * 256 + tid) * 8;
        float4 a = *(const float4*)&x[i];
        float4 b = *(const float4*)&x[i + 4];
        ushort tmp[8] = {f2bf(a.x), f2bf(a.y), f2bf(a.z), f2bf(a.w),
                         f2bf(b.x), f2bf(b.y), f2bf(b.z), f2bf(b.w)};
        *(uint4*)&xb[i] = *(const uint4*)tmp;
    } else if (bid < 2112) {
        // transpose-cast tile
        const float* src; ushort* dst; int R, C, c0, r0;
        if (bid < 1968) {
            const int idx = bid - 1536;           // 36 x 12 tiles
            src = W_attn; dst = Wat; R = CC; C = N3;
            c0 = (idx % 36) * 64; r0 = (idx / 36) * 64;
        } else {
            const int idx = bid - 1968;           // 12 x 12 tiles
            src = W_proj; dst = Wpt; R = CC; C = CC;
            c0 = (idx % 12) * 64; r0 = (idx / 12) * 64;
        }
        const int tx = tid & 63;
        const int ty = tid >> 6;
        #pragma unroll
        for (int i = 0; i < 16; ++i) {
            const int row = ty * 16 + i;
            t[tx][row] = f2bf(src[(size_t)(r0 + row) * C + c0 + tx]);
        }
        __syncthreads();
        #pragma unroll
        for (int i = 0; i < 16; ++i) {
            const int row = ty * 16 + i;
            dst[(size_t)(c0 + row) * R + r0 + tx] = t[row][tx];
        }
    } else if (bid < 5184) {
        const size_t j = ((size_t)(bid - 2112) * 256 + tid) * 4;
        float4 z = {0.f, 0.f, 0.f, 0.f};
        *(float4*)&Yacc[j] = z;
    } else {
        const size_t j = ((size_t)(bid - 5184) * 256 + tid) * 4;
        float4 z = {0.f, 0.f, 0.f, 0.f};
        *(float4*)&Lsum[j] = z;
    }
}

// ---------------------------------------------------------------------------
// Shared MFMA GEMM mainloop: C[128,128] tile, BK=64 as 2x BK=32 panels.
// ---------------------------------------------------------------------------
__device__ __forceinline__ void mfma_gemm_768(
    const ushort* __restrict__ A, const ushort* __restrict__ Bt,
    int m0, int n0, ushort* Al, ushort* Bl, f32x4 (&acc)[4][4])
{
    const int tid  = threadIdx.x;
    const int w    = tid >> 6;
    const int lane = tid & 63;
    const int quad = lane >> 4;
    const int col  = lane & 15;
    const int rm   = (w >> 1) * 64;
    const int cn   = (w & 1) * 64;

    const int row_s = tid >> 2, sub = tid & 3;
    const ushort* ga0 = A  + (size_t)(m0 + row_s) * 768 + sub * 8;
    const ushort* gb0 = Bt + (size_t)(n0 + row_s) * 768 + sub * 8;
    ushort* la0 = Al + tid * 8;
    ushort* lb0 = Bl + tid * 8;

    for (int k0 = 0; k0 < 768; k0 += 64) {
        __syncthreads();
        #pragma unroll
        for (int p = 0; p < 2; ++p) {
            const int kk = k0 + p * 32;
            __builtin_amdgcn_global_load_lds(
                (const __attribute__((address_space(1))) void*)(ga0 + kk),
                (__attribute__((address_space(3))) void*)(la0 + p*PANEL), 16, 0, 0);
            __builtin_amdgcn_global_load_lds(
                (const __attribute__((address_space(1))) void*)(ga0 + (size_t)64*768 + kk),
                (__attribute__((address_space(3))) void*)(la0 + p*PANEL + 2048), 16, 0, 0);
            __builtin_amdgcn_global_load_lds(
                (const __attribute__((address_space(1))) void*)(gb0 + kk),
                (__attribute__((address_space(3))) void*)(lb0 + p*PANEL), 16, 0, 0);
            __builtin_amdgcn_global_load_lds(
                (const __attribute__((address_space(1))) void*)(gb0 + (size_t)64*768 + kk),
                (__attribute__((address_space(3))) void*)(lb0 + p*PANEL + 2048), 16, 0, 0);
        }
        __syncthreads();

        #pragma unroll
        for (int p = 0; p < 2; ++p) {
            bf16x8 af[4], bfr[4];
            #pragma unroll
            for (int i = 0; i < 4; ++i)
                af[i] = *(const bf16x8*)&Al[p*PANEL + (rm + i*16 + col) * 32 + quad * 8];
            #pragma unroll
            for (int j = 0; j < 4; ++j)
                bfr[j] = *(const bf16x8*)&Bl[p*PANEL + (cn + j*16 + col) * 32 + quad * 8];
            #pragma unroll
            for (int i = 0; i < 4; ++i)
                #pragma unroll
                for (int j = 0; j < 4; ++j)
                    acc[i][j] = __builtin_amdgcn_mfma_f32_16x16x32_bf16(
                        af[i], bfr[j], acc[i][j], 0, 0, 0);
        }
    }
}

// ---------------------------------------------------------------------------
// Kernel: QKV GEMM (bf16 MFMA) + scatter epilogue.
// Q is pre-scaled by log2(e)/sqrt(96) so attention uses raw exp2.
// ---------------------------------------------------------------------------
__global__ __launch_bounds__(256) void qkv_mfma_kernel(
    const ushort* __restrict__ xb, const ushort* __restrict__ Wat,
    const float* __restrict__ bias,
    ushort* __restrict__ Qb, ushort* __restrict__ Kb, ushort* __restrict__ Vt)
{
    __shared__ __align__(16) ushort Al[2*PANEL];
    __shared__ __align__(16) ushort Bl[2*PANEL];
    __shared__ __align__(16) ushort Tl[4][16][20];

    const int m0 = blockIdx.y * 128;
    const int n0 = blockIdx.x * 128;
    f32x4 acc[4][4] = {};
    mfma_gemm_768(xb, Wat, m0, n0, Al, Bl, acc);

    const int tid  = threadIdx.x;
    const int w    = tid >> 6;
    const int lane = tid & 63;
    const int quad = lane >> 4;
    const int col  = lane & 15;
    const int rm   = (w >> 1) * 64;
    const int cn   = (w & 1) * 64;
    const int part = n0 / CC;
    const float scale = 0.14724442f;   // log2(e)/sqrt(96)

    if (part < 2) {
        #pragma unroll
        for (int i = 0; i < 4; ++i) {
            #pragma unroll
            for (int j = 0; j < 4; ++j) {
                const int n = n0 + cn + j*16 + col;
                const int c = n - part * CC;
                const int h = c / DD, d = c % DD;
                const float bn = bias[n];
                #pragma unroll
                for (int r = 0; r < 4; ++r) {
                    const int m = m0 + rm + i*16 + quad*4 + r;
                    const int b = m >> 11, t2 = m & 2047;
                    const int bh = b * HH + h;
                    const float v = acc[i][j][r] + bn;
                    if (part == 0) Qb[((size_t)bh*TT + t2)*DD + d] = f2bf(v * scale);
                    else           Kb[((size_t)bh*TT + t2)*DD + d] = f2bf(v);
                }
            }
        }
    } else {
        #pragma unroll
        for (int i = 0; i < 4; ++i) {
            #pragma unroll
            for (int j = 0; j < 4; ++j) {
                const int n = n0 + cn + j*16 + col;
                const float bn = bias[n];
                ushort4 tv;
                tv.x = f2bf(acc[i][j][0] + bn);
                tv.y = f2bf(acc[i][j][1] + bn);
                tv.z = f2bf(acc[i][j][2] + bn);
                tv.w = f2bf(acc[i][j][3] + bn);
                *(ushort4*)&Tl[w][col][quad * 4] = tv;
                #pragma unroll
                for (int rr = 0; rr < 4; ++rr) {
                    const int c = n0 - 2*CC + cn + j*16 + quad*4 + rr;
                    const int h = c / DD, d = c % DD;
                    const int m = m0 + rm + i*16 + col;
                    const int b = m >> 11, t2 = m & 2047;
                    Vt[((size_t)(b*HH + h)*DD + d)*TT + t2] = Tl[w][quad*4 + rr][col];
                }
            }
        }
    }
}

// ---------------------------------------------------------------------------
// Kernel: flash attention, split-K partials, transposed score tile (R8).
// Epilogue: fp32 atomic-accumulate partial O into Yacc [4096][768] and
// l into Lsum [16][2048] — removes the combine kernel entirely.
// ---------------------------------------------------------------------------
__global__ __launch_bounds__(256) void attn_mfma_kernel(
    const ushort* __restrict__ Qb, const ushort* __restrict__ Kb,
    const ushort* __restrict__ Vt, float* __restrict__ Yacc,
    float* __restrict__ Lsum)
{
    __shared__ __align__(16) ushort Kl[64][104];     // [key][d], +8 pad
    __shared__ __align__(16) ushort Vl[112][72];     // [d][key]; row 96 = ones
    __shared__ __align__(16) ushort Pl[4][16][72];   // per-wave P^T: [q][key]

    const int it  = blockIdx.x;       // 0..1279
    const int bh  = it / 80;
    const int rem = it % 80;
    int qb, ci;
    if (rem < 8)       { qb = rem;               ci = 0; }
    else if (rem < 24) { int t = rem - 8;  qb = 8  + t/2; ci = t % 2; }
    else if (rem < 48) { int t = rem - 24; qb = 16 + t/3; ci = t % 3; }
    else               { int t = rem - 48; qb = 24 + t/4; ci = t % 4; }

    const int tid  = threadIdx.x;
    const int w    = tid >> 6;
    const int lane = tid & 63;
    const int quad = lane >> 4;
    const int col  = lane & 15;
    const int q0   = qb * 64;

    const int qrow = q0 + w*16 + col;
    const ushort* Qp = Qb + ((size_t)bh*TT + qrow)*DD;
    bf16x8 qf[3];
    #pragma unroll
    for (int ks = 0; ks < 3; ++ks)
        qf[ks] = *(const bf16x8*)(Qp + ks*32 + quad*8);

    const ushort* Kg = Kb + (size_t)bh*TT*DD;
    const ushort* Vg = Vt + (size_t)bh*DD*TT;

    if (tid < 64) Vl[96][tid] = 0x3F80;   // bf16 1.0 ones-row

    f32x4 O[7] = {};                      // O^T; O[6][0] (quad 0) = l

    const int kts = ci * 8;
    const int kte = min(kts + 8, qb + 1);

    for (int kt = kts; kt < kte; ++kt) {
        const int k0 = kt * 64;
        __syncthreads();
        #pragma unroll
        for (int i = 0; i < 3; ++i) {
            int l = tid + i*256;
            int row = l / 12, ch = l % 12;
            uint4 vv = *(const uint4*)(Kg + (size_t)(k0 + row)*DD + ch*8);
            *(uint4*)&Kl[row][ch*8] = vv;
        }
        #pragma unroll
        for (int i = 0; i < 3; ++i) {
            int l = tid + i*256;
            int row = l / 8, ch = l % 8;
            uint4 vv = *(const uint4*)(Vg + (size_t)row*TT + k0 + ch*8);
            *(uint4*)&Vl[row][ch*8] = vv;
        }
        __syncthreads();

        // ---- S^T tiles (key-major) + exp2 + key-contiguous P^T store ----
        #pragma unroll
        for (int c = 0; c < 4; ++c) {
            f32x4 a = {0.f, 0.f, 0.f, 0.f};
            #pragma unroll
            for (int ks = 0; ks < 3; ++ks) {
                bf16x8 kf = *(const bf16x8*)&Kl[c*16 + col][ks*32 + quad*8];
                a = __builtin_amdgcn_mfma_f32_16x16x32_bf16(kf, qf[ks], a, 0, 0, 0);
            }
            if (kt == qb) {       // causal mask: key_local > q_local
                #pragma unroll
                for (int r = 0; r < 4; ++r)
                    if (c*16 + quad*4 + r > w*16 + col) a[r] = -1e30f;
            }
            const unsigned u0 = pk2(__builtin_amdgcn_exp2f(a[0]),
                                    __builtin_amdgcn_exp2f(a[1]));
            const unsigned u1 = pk2(__builtin_amdgcn_exp2f(a[2]),
                                    __builtin_amdgcn_exp2f(a[3]));
            uint2 uu; uu.x = u0; uu.y = u1;
            *(uint2*)&Pl[w][col][c*16 + quad*4] = uu;   // P^T[q=col][4 keys]
        }

        bf16x8 pf0 = *(const bf16x8*)&Pl[w][col][quad*8];        // keys 0..31
        bf16x8 pf1 = *(const bf16x8*)&Pl[w][col][32 + quad*8];   // keys 32..63

        // ---- O^T += V_A x P^T_B : 7 d-tiles x 2 k-steps ----
        #pragma unroll
        for (int c2 = 0; c2 < 7; ++c2) {
            bf16x8 vb0 = *(const bf16x8*)&Vl[c2*16 + col][quad*8];
            bf16x8 vb1 = *(const bf16x8*)&Vl[c2*16 + col][32 + quad*8];
            O[c2] = __builtin_amdgcn_mfma_f32_16x16x32_bf16(vb0, pf0, O[c2], 0, 0, 0);
            O[c2] = __builtin_amdgcn_mfma_f32_16x16x32_bf16(vb1, pf1, O[c2], 0, 0, 0);
        }
    }

    // ---- epilogue: atomic fp32 accumulate into Yacc / Lsum ----
    const int b = bh >> 3, h = bh & 7;
    const int q = q0 + w*16 + col;
    float* Yp = Yacc + ((size_t)b*TT + q)*CC + h*DD;
    #pragma unroll
    for (int c2 = 0; c2 < 6; ++c2)
        #pragma unroll
        for (int r = 0; r < 4; ++r)
            atomicAdd(&Yp[c2*16 + quad*4 + r], O[c2][r]);
    if (quad == 0)
        atomicAdd(&Lsum[(size_t)bh*TT + q], O[6][0]);
}

// ---------------------------------------------------------------------------
// Kernel: proj GEMM with fused combine. A-staging reads Yacc fp32,
// scales by 1/Lsum (per row m, per head h = k/96), converts to bf16 -> LDS.
// B (Wpt) stays on global_load_lds. out = (Yacc/L) @ W_proj + b_proj.
// ---------------------------------------------------------------------------
__global__ __launch_bounds__(256) void proj_mfma_kernel(
    const float* __restrict__ Yacc, const float* __restrict__ Lsum,
    const ushort* __restrict__ Wpt, const float* __restrict__ bias,
    float* __restrict__ out)
{
    __shared__ __align__(16) ushort Al[2*PANEL];
    __shared__ __align__(16) ushort Bl[2*PANEL];

    const int m0 = blockIdx.y * 128;
    const int n0 = blockIdx.x * 128;

    const int tid  = threadIdx.x;
    const int w    = tid >> 6;
    const int lane = tid & 63;
    const int quad = lane >> 4;
    const int col  = lane & 15;
    const int rm   = (w >> 1) * 64;
    const int cn   = (w & 1) * 64;

    const int row_s = tid >> 2, sub = tid & 3;
    const ushort* gb0 = Wpt + (size_t)(n0 + row_s) * 768 + sub * 8;
    ushort* lb0 = Bl + tid * 8;

    f32x4 acc[4][4] = {};

    for (int k0 = 0; k0 < 768; k0 += 64) {
        __syncthreads();
        // B: async global->LDS
        #pragma unroll
        for (int p = 0; p < 2; ++p) {
            const int kk = k0 + p * 32;
            __builtin_amdgcn_global_load_lds(
                (const __attribute__((address_space(1))) void*)(gb0 + kk),
                (__attribute__((address_space(3))) void*)(lb0 + p*PANEL), 16, 0, 0);
            __builtin_amdgcn_global_load_lds(
                (const __attribute__((address_space(1))) void*)(gb0 + (size_t)64*768 + kk),
                (__attribute__((address_space(3))) void*)(lb0 + p*PANEL + 2048), 16, 0, 0);
        }
        // A: fp32 Yacc * invL -> bf16 -> LDS (8-elem chunk never straddles heads)
        #pragma unroll
        for (int p = 0; p < 2; ++p) {
            const int kk = k0 + p*32 + sub*8;
            const int h  = kk / DD;
            #pragma unroll
            for (int half = 0; half < 2; ++half) {
                const int m = m0 + half*64 + row_s;
                const int b = m >> 11, t2 = m & 2047;
                const float iL = 1.0f / Lsum[(size_t)(b*HH + h)*TT + t2];
                const float* ga = Yacc + (size_t)m*768 + kk;
                float4 v0 = *(const float4*)ga;
                float4 v1 = *(const float4*)(ga + 4);
                ushort tmp[8] = {f2bf(v0.x*iL), f2bf(v0.y*iL), f2bf(v0.z*iL), f2bf(v0.w*iL),
                                 f2bf(v1.x*iL), f2bf(v1.y*iL), f2bf(v1.z*iL), f2bf(v1.w*iL)};
                *(uint4*)(Al + p*PANEL + half*2048 + tid*8) = *(const uint4*)tmp;
            }
        }
        __syncthreads();

        #pragma unroll
        for (int p = 0; p < 2; ++p) {
            bf16x8 af[4], bfr[4];
            #pragma unroll
            for (int i = 0; i < 4; ++i)
                af[i] = *(const bf16x8*)&Al[p*PANEL + (rm + i*16 + col) * 32 + quad * 8];
            #pragma unroll
            for (int j = 0; j < 4; ++j)
                bfr[j] = *(const bf16x8*)&Bl[p*PANEL + (cn + j*16 + col) * 32 + quad * 8];
            #pragma unroll
            for (int i = 0; i < 4; ++i)
                #pragma unroll
                for (int j = 0; j < 4; ++j)
                    acc[i][j] = __builtin_amdgcn_mfma_f32_16x16x32_bf16(
                        af[i], bfr[j], acc[i][j], 0, 0, 0);
        }
    }

    #pragma unroll
    for (int i = 0; i < 4; ++i) {
        #pragma unroll
        for (int j = 0; j < 4; ++j) {
            const int n = n0 + cn + j*16 + col;
            const float bn = bias[n];
            #pragma unroll
            for (int r = 0; r < 4; ++r) {
                const int m = m0 + rm + i*16 + quad*4 + r;
                out[(size_t)m*CC + n] = acc[i][j][r] + bn;
            }
        }
    }
}

extern "C" void kernel_launch(void* const* d_in, const int* in_sizes, int n_in,
                              void* d_out, int out_size, void* d_ws, size_t ws_size,
                              hipStream_t stream) {
    const float* x      = (const float*)d_in[0];
    const float* W_attn = (const float*)d_in[1];
    const float* b_attn = (const float*)d_in[2];
    const float* W_proj = (const float*)d_in[3];
    const float* b_proj = (const float*)d_in[4];
    float* out = (float*)d_out;

    const size_t SLICE = (size_t)BH * TT * DD;     // 3,145,728
    ushort* xb   = (ushort*)d_ws;                  // bf16 [4096][768]
    ushort* Qb   = xb  + SLICE;                    // bf16 [BH][T][96] pre-scaled
    ushort* Kb   = Qb  + SLICE;                    // bf16 [BH][T][96]
    ushort* Vt   = Kb  + SLICE;                    // bf16 [BH][96][T]
    ushort* Wat  = Vt  + SLICE;                    // bf16 [2304][768]
    ushort* Wpt  = Wat + (size_t)N3 * CC;          // bf16 [768][768]
    float*  Yacc = (float*)(Wpt + (size_t)CC * CC);   // fp32 [4096][768]
    float*  Lsum = Yacc + (size_t)BB * TT * CC;       // fp32 [16][2048]

    prep_kernel<<<dim3(PREP_BLOCKS), 256, 0, stream>>>(
        x, W_attn, W_proj, xb, Wat, Wpt, Yacc, Lsum);
    qkv_mfma_kernel<<<dim3(N3/128, (BB*TT)/128), 256, 0, stream>>>(
        xb, Wat, b_attn, Qb, Kb, Vt);
    attn_mfma_kernel<<<dim3(1280), 256, 0, stream>>>(
        Qb, Kb, Vt, Yacc, Lsum);
    proj_mfma_kernel<<<dim3(CC/128, (BB*TT)/128), 256, 0, stream>>>(
        Yacc, Lsum, Wpt, b_proj, out);
}